// Round 6
// baseline (230.881 us; speedup 1.0000x reference)
//
#include <hip/hip_runtime.h>
#include <cstdint>
#include <cmath>

#define B_ 4
#define H_ 256
#define C_ 80
#define TX_ 256
#define TY_ 1024
#define NC_ 64                 // chunks of 16 columns
#define NEGF (-1e9f)

// output layout (floats): o_en_ex [B,H,TY] | logp [B,TX,TY] | attn [B,TX,TY] | dr [B,TX]
#define OFF_LOGP (B_*H_*TY_)
#define OFF_ATTN (OFF_LOGP + B_*TX_*TY_)
#define OFF_DR   (OFF_ATTN + B_*TX_*TY_)

// __shfl_up(x,1) as pure VALU: DPP wave_shr:1 (ctrl 0x138); lane 0 gets NEGF.
__device__ __forceinline__ float dpp_shr1_negfill_f32(float x) {
  union { float f; int i; } u, o, r;
  u.f = x; o.f = NEGF;
  r.i = __builtin_amdgcn_update_dpp(o.i, u.i, 0x138, 0xf, 0xf, false);
  return r.f;
}

// ---------------------------------------------------------------------------
// Kernel A: logp[b,x,t] = -0.5*mean_c((y-mu)^2*exp(-2 ls)) - 0.5*mean_c(ls)
// Expanded form: (y-mu)^2 w = (w*y + m1)*y + w*mu^2, m1 = -2*w*mu; the
// constant K = sum_c w*mu^2 is folded out of the t-loop (48->36 f64/c).
// f64 accumulate, f32 store (threshold-safe; DP consumes the f32 values).
// Also writes masked+transposed lpT[b,t,x] into the attn output region.
// ---------------------------------------------------------------------------
__global__ __launch_bounds__(256) void k_logp(
    const float* __restrict__ mu, const float* __restrict__ ls,
    const float* __restrict__ y, const int* __restrict__ xlp,
    const int* __restrict__ ylp, float* __restrict__ logp_out,
    float* __restrict__ lpT)
{
  const int b  = blockIdx.y;
  const int x0 = blockIdx.x * 4;     // 4 x's per block
  const int tid = threadIdx.x;
  __shared__ double s_w[4][C_];
  __shared__ double s_m1[4][C_];
  __shared__ double s_wm2[4][C_];
  __shared__ double s_lsv[4][C_];
  __shared__ double s_K[4];
  __shared__ double s_t0[4];
  __shared__ float tile[TY_][4];     // [t][xi] transposed tile, 16 KB
  for (int i = tid; i < 4 * C_; i += 256) {
    int xi = i / C_, c = i - xi * C_;
    double m = (double)mu[(b * C_ + c) * TX_ + x0 + xi];
    double l = (double)ls[(b * C_ + c) * TX_ + x0 + xi];
    double w = exp(-2.0 * l);
    s_w[xi][c]   = w;
    s_m1[xi][c]  = -2.0 * w * m;
    s_wm2[xi][c] = w * m * m;
    s_lsv[xi][c] = l;
  }
  __syncthreads();
  {
    int xi = tid >> 6, cc = tid & 63;
    double kp = (cc < C_) ? s_wm2[xi][cc] : 0.0;
    double tp = (cc < C_) ? s_lsv[xi][cc] : 0.0;
    if (cc + 64 < C_) { kp += s_wm2[xi][cc + 64]; tp += s_lsv[xi][cc + 64]; }
#pragma unroll
    for (int off = 32; off; off >>= 1) {
      kp += __shfl_down(kp, off);
      tp += __shfl_down(tp, off);
    }
    if (cc == 0) { s_K[xi] = kp; s_t0[xi] = -0.5 * (tp * (1.0 / C_)); }
  }
  __syncthreads();

  const int t0 = tid * 4;
  double acc[4][4];
#pragma unroll
  for (int xi = 0; xi < 4; ++xi)
#pragma unroll
    for (int k = 0; k < 4; ++k) acc[xi][k] = 0.0;

  const float4* yp = (const float4*)(y + (size_t)b * C_ * TY_) + tid;
#pragma unroll 4
  for (int c = 0; c < C_; ++c) {
    float4 yv = yp[c * (TY_ / 4)];
    double y0 = yv.x, y1 = yv.y, y2 = yv.z, y3 = yv.w;
#pragma unroll
    for (int xi = 0; xi < 4; ++xi) {
      double w = s_w[xi][c], m1 = s_m1[xi][c];
      double u0 = fma(w, y0, m1), u1 = fma(w, y1, m1);
      double u2 = fma(w, y2, m1), u3 = fma(w, y3, m1);
      acc[xi][0] = fma(u0, y0, acc[xi][0]);
      acc[xi][1] = fma(u1, y1, acc[xi][1]);
      acc[xi][2] = fma(u2, y2, acc[xi][2]);
      acc[xi][3] = fma(u3, y3, acc[xi][3]);
    }
  }

  const int xlen = xlp[b], ylen = ylp[b];
#pragma unroll
  for (int xi = 0; xi < 4; ++xi) {
    int x = x0 + xi;
    double c0 = s_t0[xi], K = s_K[xi];
    float r[4];
#pragma unroll
    for (int k = 0; k < 4; ++k)
      r[k] = (float)((acc[xi][k] + K) * (-0.5 / C_) + c0);
    *(float4*)&logp_out[((size_t)(b * TX_ + x)) * TY_ + t0] =
        make_float4(r[0], r[1], r[2], r[3]);
    bool xm = x < xlen;
#pragma unroll
    for (int k = 0; k < 4; ++k)
      tile[t0 + k][xi] = (xm && (t0 + k) < ylen) ? r[k] : NEGF;
  }
  __syncthreads();

  float* dst = lpT + (size_t)b * TY_ * TX_ + x0;
  const float4* tp = (const float4*)tile;
#pragma unroll
  for (int k = 0; k < 4; ++k) {
    int t = tid + 256 * k;           // consecutive lanes -> consecutive t
    *(float4*)&dst[(size_t)t * TX_] = tp[t];
  }
}

// ---------------------------------------------------------------------------
// Kernel B1 (forward DP): 2 waves. Wave 1 = software-pipelined producer:
// per chunk, ds_write chunk c+1 (loaded LAST iteration, so global latency is
// hidden across a full chunk) then issue loads for chunk c+2. Wave 0 =
// consumer: f32 DP (same op order as the np f32 reference -> near-bit-exact),
// DPP lane shift (no LDS in the recurrence), diag bits packed 32/word and
// stored straight to global (coalesced uint4 every 32 columns).
// LDS: 2 x 16 cols x 1KB ring = 32 KB.
// ---------------------------------------------------------------------------
__global__ __launch_bounds__(128) void k_fwd(
    const float* __restrict__ lpT, uint32_t* __restrict__ bits_g)
{
  const int b = blockIdx.x;
  const int lane = threadIdx.x & 63;
  const int wid  = threadIdx.x >> 6;
  __shared__ float ring[2 * 16 * 256];       // 32 KB
  const float* gb = lpT + (size_t)b * TY_ * TX_;
  uint32_t* bg = bits_g + b * 8192;

  float v0 = 0.f, v1 = 0.f, v2 = 0.f, v3 = 0.f, sh = NEGF;
  uint32_t b0 = 0, b1 = 0, b2 = 0, b3 = 0;
  float4 v[16];

  if (wid == 1) {
    const float4* src = (const float4*)gb + lane;
#pragma unroll
    for (int i = 0; i < 16; ++i) v[i] = src[i * 64];          // chunk 0
#pragma unroll
    for (int i = 0; i < 16; ++i)
      *(float4*)&ring[i * 256 + 4 * lane] = v[i];             // write buf0
#pragma unroll
    for (int i = 0; i < 16; ++i) v[i] = src[(16 + i) * 64];   // chunk 1
  } else {
    v0 = (lane == 0) ? 0.0f : NEGF;
    v1 = v2 = v3 = NEGF;
  }
  __syncthreads();

  for (int c = 0; c < NC_; ++c) {
    if (wid == 1) {
      if (c + 1 < NC_) {          // write chunk c+1 (regs) -> buf (c+1)&1
        const uint32_t nb = ((c + 1) & 1) * 4096;
#pragma unroll
        for (int i = 0; i < 16; ++i)
          *(float4*)&ring[nb + i * 256 + 4 * lane] = v[i];
      }
      if (c + 2 < NC_) {          // issue loads chunk c+2 (consumed next iter)
        const float4* s2 = (const float4*)(gb + (size_t)(c + 2) * 16 * TX_) + lane;
#pragma unroll
        for (int i = 0; i < 16; ++i) v[i] = s2[i * 64];
      }
    } else if (wid == 0) {
      const uint32_t rb = (c & 1) * 4096;
      float4 cl[16];
#pragma unroll
      for (int i = 0; i < 16; ++i)
        cl[i] = *(const float4*)&ring[rb + i * 256 + 4 * lane];
#pragma unroll
      for (int i = 0; i < 16; ++i) {
        const int t = c * 16 + i;
        const float vs0 = sh;           // lane 0 already NEGF via DPP old
        uint32_t bit = 1u << (t & 31);
        if (vs0 > v0) b0 |= bit;        // diag = v_shift > v (pre-update)
        if (v0 > v1)  b1 |= bit;
        if (v1 > v2)  b2 |= bit;
        if (v2 > v3)  b3 |= bit;
        float nv3 = cl[i].w + fmaxf(v3, v2);
        sh = dpp_shr1_negfill_f32(nv3); // pure VALU lane shift
        float nv2 = cl[i].z + fmaxf(v2, v1);
        float nv1 = cl[i].y + fmaxf(v1, v0);
        float nv0 = cl[i].x + fmaxf(v0, vs0);
        v0 = nv0; v1 = nv1; v2 = nv2; v3 = nv3;
        if ((t & 31) == 31) {
          int w = t >> 5;
          uint4 pk; pk.x = b0; pk.y = b1; pk.z = b2; pk.w = b3;
          *(uint4*)&bg[w * 256 + 4 * lane] = pk;   // coalesced 1KB/wave
          b0 = b1 = b2 = b3 = 0;
        }
      }
    }
    __syncthreads();
  }
}

// ---------------------------------------------------------------------------
// Kernel B2 (backtrack): one wave per batch. Coalesced bits load -> LDS,
// serial run-length walk (lane 0), then wave scan -> cum/dr/xt.
// bits layout: bits[w*256 + x], w = t>>5.
// ---------------------------------------------------------------------------
__global__ __launch_bounds__(64) void k_bwd(
    const uint32_t* __restrict__ bits_g, const int* __restrict__ xlp,
    const int* __restrict__ ylp, float* __restrict__ dr_out,
    int* __restrict__ cum_ws, int* __restrict__ xt_ws)
{
  const int b = blockIdx.x;
  const int lane = threadIdx.x;
  __shared__ uint32_t bits[8192];            // 32 KB
  __shared__ uint32_t dur[TX_];

  const uint4* src = (const uint4*)(bits_g + b * 8192) + lane;
#pragma unroll 4
  for (int i = 0; i < 32; ++i)
    *(uint4*)&bits[i * 256 + 4 * lane] = src[i * 64];
#pragma unroll
  for (int j = 0; j < 4; ++j) dur[4 * lane + j] = 0;
  __syncthreads();

  const int xlen = xlp[b], ylen = ylp[b];
  if (lane == 0) {
    int idx = xlen - 1;
    int t = ylen - 1;
    while (t >= 0) {
      if (idx == 0) { dur[0] += (uint32_t)(t + 1); break; }
      int w = t >> 5, rr = t & 31;
      uint32_t word = bits[w * 256 + idx];
      word &= (rr == 31) ? 0xffffffffu : ((1u << (rr + 1)) - 1u);
      while (word == 0 && w > 0) { --w; word = bits[w * 256 + idx]; }
      if (word == 0) { dur[idx] += (uint32_t)(t + 1); break; }
      int bitpos = 31 - __builtin_clz(word);
      int tp = (w << 5) | bitpos;        // step where diag fires -> decrement
      dur[idx] += (uint32_t)(t - tp + 1);
      --idx;
      t = tp - 1;
    }
  }
  __syncthreads();

  // wave-wide inclusive scan of durations -> cum, dr, and t->x scatter map
  uint32_t d0 = dur[4 * lane], d1 = dur[4 * lane + 1];
  uint32_t d2 = dur[4 * lane + 2], d3 = dur[4 * lane + 3];
  uint32_t own = d0 + d1 + d2 + d3;
  uint32_t s = own;
#pragma unroll
  for (int off = 1; off < 64; off <<= 1) {
    uint32_t n = __shfl_up(s, off);
    if (lane >= off) s += n;
  }
  uint32_t base = s - own;
  uint32_t c0 = base + d0, c1 = c0 + d1, c2 = c1 + d2, c3 = c2 + d3;
  int x = 4 * lane;
  cum_ws[b * TX_ + x]     = (int)c0;
  cum_ws[b * TX_ + x + 1] = (int)c1;
  cum_ws[b * TX_ + x + 2] = (int)c2;
  cum_ws[b * TX_ + x + 3] = (int)c3;
  dr_out[b * TX_ + x]     = (float)d0;
  dr_out[b * TX_ + x + 1] = (float)d1;
  dr_out[b * TX_ + x + 2] = (float)d2;
  dr_out[b * TX_ + x + 3] = (float)d3;
  int* xt = xt_ws + b * TY_;
  for (uint32_t t = c0 - d0; t < c0; ++t) xt[t] = x;
  for (uint32_t t = c1 - d1; t < c1; ++t) xt[t] = x + 1;
  for (uint32_t t = c2 - d2; t < c2; ++t) xt[t] = x + 2;
  for (uint32_t t = c3 - d3; t < c3; ++t) xt[t] = x + 3;
}

// ---------------------------------------------------------------------------
// Kernel C (fused epilogue): blocks [0,TX) write attn rows from cum;
// blocks [TX,TX+H) gather o_en_ex[b,h,t] = t<ylen ? en[b,h,xt[b,t]] : 0.
// ---------------------------------------------------------------------------
__global__ __launch_bounds__(256) void k_epi(
    const int* __restrict__ cum_ws, const int* __restrict__ xt_ws,
    const float* __restrict__ en, const int* __restrict__ ylp,
    float* __restrict__ attn, float* __restrict__ oen)
{
  const int b = blockIdx.y, bx = blockIdx.x, tid = threadIdx.x;
  __shared__ float row[TX_];
  if (bx < TX_) {
    const int x = bx;
    int hi = cum_ws[b * TX_ + x];
    int lo = (x > 0) ? cum_ws[b * TX_ + x - 1] : 0;
    int t0 = tid * 4;
    float4 v;
    v.x = (t0     >= lo && t0     < hi) ? 1.f : 0.f;
    v.y = (t0 + 1 >= lo && t0 + 1 < hi) ? 1.f : 0.f;
    v.z = (t0 + 2 >= lo && t0 + 2 < hi) ? 1.f : 0.f;
    v.w = (t0 + 3 >= lo && t0 + 3 < hi) ? 1.f : 0.f;
    *(float4*)&attn[((size_t)(b * TX_ + x)) * TY_ + t0] = v;
  } else {
    const int h = bx - TX_;
    row[tid] = en[((size_t)(b * H_ + h)) * TX_ + tid];
    __syncthreads();
    const int ylen = ylp[b];
    int t0 = tid * 4;
    int4 xi = *(const int4*)&xt_ws[b * TY_ + t0];
    float4 v;
    v.x = (t0     < ylen) ? row[xi.x & (TX_ - 1)] : 0.f;
    v.y = (t0 + 1 < ylen) ? row[xi.y & (TX_ - 1)] : 0.f;
    v.z = (t0 + 2 < ylen) ? row[xi.z & (TX_ - 1)] : 0.f;
    v.w = (t0 + 3 < ylen) ? row[xi.w & (TX_ - 1)] : 0.f;
    *(float4*)&oen[((size_t)(b * H_ + h)) * TY_ + t0] = v;
  }
}

extern "C" void kernel_launch(void* const* d_in, const int* in_sizes, int n_in,
                              void* d_out, int out_size, void* d_ws, size_t ws_size,
                              hipStream_t stream)
{
  const float* en = (const float*)d_in[0];
  const float* mu = (const float*)d_in[1];
  const float* ls = (const float*)d_in[2];
  const float* y  = (const float*)d_in[3];
  const int*   xl = (const int*)d_in[4];
  const int*   yl = (const int*)d_in[5];

  float* out  = (float*)d_out;
  float* oen  = out;             // [B,H,TY]
  float* logp = out + OFF_LOGP;  // [B,TX,TY]
  float* attn = out + OFF_ATTN;  // [B,TX,TY] (doubles as lpT scratch first)
  float* dr   = out + OFF_DR;    // [B,TX]

  int* cum = (int*)d_ws;               // B*TX ints
  int* xt  = cum + B_ * TX_;           // B*TY ints
  uint32_t* bits = (uint32_t*)(xt + B_ * TY_);  // B*8192 words

  k_logp<<<dim3(TX_ / 4, B_),   256, 0, stream>>>(mu, ls, y, xl, yl, logp, attn);
  k_fwd <<<B_,                  128, 0, stream>>>(attn, bits);
  k_bwd <<<B_,                   64, 0, stream>>>(bits, xl, yl, dr, cum, xt);
  k_epi <<<dim3(TX_ + H_, B_),  256, 0, stream>>>(cum, xt, en, yl, attn, oen);
}

// Round 7
// 203.911 us; speedup vs baseline: 1.1323x; 1.1323x over previous
//
#include <hip/hip_runtime.h>
#include <cstdint>
#include <cmath>

#define B_ 4
#define H_ 256
#define C_ 80
#define TX_ 256
#define TY_ 1024
#define NC_ 64                 // chunks of 16 columns
#define NEGF (-1e9f)

// output layout (floats): o_en_ex [B,H,TY] | logp [B,TX,TY] | attn [B,TX,TY] | dr [B,TX]
#define OFF_LOGP (B_*H_*TY_)
#define OFF_ATTN (OFF_LOGP + B_*TX_*TY_)
#define OFF_DR   (OFF_ATTN + B_*TX_*TY_)

// __shfl_up(x,1) as pure VALU: DPP wave_shr:1 (ctrl 0x138); lane 0 gets NEGF.
__device__ __forceinline__ float dpp_shr1_negfill_f32(float x) {
  union { float f; int i; } u, o, r;
  u.f = x; o.f = NEGF;
  r.i = __builtin_amdgcn_update_dpp(o.i, u.i, 0x138, 0xf, 0xf, false);
  return r.f;
}

// ---------------------------------------------------------------------------
// Kernel A: logp[b,x,t] = -0.5*mean_c((y-mu)^2*exp(-2 ls)) - 0.5*mean_c(ls)
// Expanded: (y-mu)^2 w = (w*y + m1)*y + w*mu^2, m1 = -2*w*mu; K = sum w*mu^2
// folded out of the t-loop.  f64 accumulate, f32 store.
// Also writes masked+transposed lpT[b,t,x] into the attn output region.
// ---------------------------------------------------------------------------
__global__ __launch_bounds__(256) void k_logp(
    const float* __restrict__ mu, const float* __restrict__ ls,
    const float* __restrict__ y, const int* __restrict__ xlp,
    const int* __restrict__ ylp, float* __restrict__ logp_out,
    float* __restrict__ lpT)
{
  const int b  = blockIdx.y;
  const int x0 = blockIdx.x * 4;     // 4 x's per block
  const int tid = threadIdx.x;
  __shared__ double s_w[4][C_];
  __shared__ double s_m1[4][C_];
  __shared__ double s_wm2[4][C_];
  __shared__ double s_lsv[4][C_];
  __shared__ double s_K[4];
  __shared__ double s_t0[4];
  __shared__ float tile[TY_][4];     // [t][xi] transposed tile, 16 KB
  for (int i = tid; i < 4 * C_; i += 256) {
    int xi = i / C_, c = i - xi * C_;
    double m = (double)mu[(b * C_ + c) * TX_ + x0 + xi];
    double l = (double)ls[(b * C_ + c) * TX_ + x0 + xi];
    double w = exp(-2.0 * l);
    s_w[xi][c]   = w;
    s_m1[xi][c]  = -2.0 * w * m;
    s_wm2[xi][c] = w * m * m;
    s_lsv[xi][c] = l;
  }
  __syncthreads();
  {
    int xi = tid >> 6, cc = tid & 63;
    double kp = (cc < C_) ? s_wm2[xi][cc] : 0.0;
    double tp = (cc < C_) ? s_lsv[xi][cc] : 0.0;
    if (cc + 64 < C_) { kp += s_wm2[xi][cc + 64]; tp += s_lsv[xi][cc + 64]; }
#pragma unroll
    for (int off = 32; off; off >>= 1) {
      kp += __shfl_down(kp, off);
      tp += __shfl_down(tp, off);
    }
    if (cc == 0) { s_K[xi] = kp; s_t0[xi] = -0.5 * (tp * (1.0 / C_)); }
  }
  __syncthreads();

  const int t0 = tid * 4;
  double acc[4][4];
#pragma unroll
  for (int xi = 0; xi < 4; ++xi)
#pragma unroll
    for (int k = 0; k < 4; ++k) acc[xi][k] = 0.0;

  const float4* yp = (const float4*)(y + (size_t)b * C_ * TY_) + tid;
#pragma unroll 4
  for (int c = 0; c < C_; ++c) {
    float4 yv = yp[c * (TY_ / 4)];
    double y0 = yv.x, y1 = yv.y, y2 = yv.z, y3 = yv.w;
#pragma unroll
    for (int xi = 0; xi < 4; ++xi) {
      double w = s_w[xi][c], m1 = s_m1[xi][c];
      double u0 = fma(w, y0, m1), u1 = fma(w, y1, m1);
      double u2 = fma(w, y2, m1), u3 = fma(w, y3, m1);
      acc[xi][0] = fma(u0, y0, acc[xi][0]);
      acc[xi][1] = fma(u1, y1, acc[xi][1]);
      acc[xi][2] = fma(u2, y2, acc[xi][2]);
      acc[xi][3] = fma(u3, y3, acc[xi][3]);
    }
  }

  const int xlen = xlp[b], ylen = ylp[b];
#pragma unroll
  for (int xi = 0; xi < 4; ++xi) {
    int x = x0 + xi;
    double c0 = s_t0[xi], K = s_K[xi];
    float r[4];
#pragma unroll
    for (int k = 0; k < 4; ++k)
      r[k] = (float)((acc[xi][k] + K) * (-0.5 / C_) + c0);
    *(float4*)&logp_out[((size_t)(b * TX_ + x)) * TY_ + t0] =
        make_float4(r[0], r[1], r[2], r[3]);
    bool xm = x < xlen;
#pragma unroll
    for (int k = 0; k < 4; ++k)
      tile[t0 + k][xi] = (xm && (t0 + k) < ylen) ? r[k] : NEGF;
  }
  __syncthreads();

  float* dst = lpT + (size_t)b * TY_ * TX_ + x0;
  const float4* tp = (const float4*)tile;
#pragma unroll
  for (int k = 0; k < 4; ++k) {
    int t = tid + 256 * k;           // consecutive lanes -> consecutive t
    *(float4*)&dst[(size_t)t * TX_] = tp[t];
  }
}

// ---------------------------------------------------------------------------
// Kernel B: Viterbi DP fwd + backtrack, ONE wave per batch, no LDS in the
// forward path.  Triple-buffered register prefetch: float4 BA/BB/BC[16]
// (192 VGPRs, __launch_bounds__(64,1) opens the 512-VGPR budget), loads for
// chunk c+2 issued while consuming chunk c — R6's 197 cyc/iter was the
// compiler sinking ds_reads to their uses at VGPR=68; keeping columns in
// registers removes all latency from the recurrence.  Diag bits -> LDS;
// backtrack + scan fused (saves the R6 global round-trip + launch).
// ---------------------------------------------------------------------------
__global__ __launch_bounds__(64, 1) void k_dp(
    const float* __restrict__ lpT, const int* __restrict__ xlp,
    const int* __restrict__ ylp, float* __restrict__ dr_out,
    int* __restrict__ cum_ws, int* __restrict__ xt_ws)
{
  const int b = blockIdx.x;
  const int lane = threadIdx.x;
  __shared__ uint32_t bits[8192];            // [w*256 + x], 32 KB
  __shared__ uint32_t dur[TX_];

  const float4* src = (const float4*)(lpT + (size_t)b * TY_ * TX_) + lane;
  // column t lives at src[t*64]

  float v0 = (lane == 0) ? 0.0f : NEGF, v1 = NEGF, v2 = NEGF, v3 = NEGF;
  float sh = NEGF;
  uint32_t b0 = 0, b1 = 0, b2 = 0, b3 = 0;

  float4 BA[16], BB[16], BC[16];
#pragma unroll
  for (int i = 0; i < 16; ++i) BA[i] = src[i * 64];          // chunk 0
#pragma unroll
  for (int i = 0; i < 16; ++i) BB[i] = src[(16 + i) * 64];   // chunk 1

  // body: issue loads for chunk c+2 into LD, consume chunk c from CUR
#define DP_BODY(CUR, LD, c)                                                  \
  {                                                                          \
    const int tl = ((c) + 2 < NC_ ? (c) + 2 : NC_ - 1) * 16;                 \
    _Pragma("unroll")                                                        \
    for (int i = 0; i < 16; ++i) LD[i] = src[(tl + i) * 64];                 \
    _Pragma("unroll")                                                        \
    for (int i = 0; i < 16; ++i) {                                           \
      const int t = (c) * 16 + i;                                            \
      const float vs0 = sh;                                                  \
      uint32_t bit = 1u << (t & 31);                                         \
      if (vs0 > v0) b0 |= bit;                                               \
      if (v0 > v1)  b1 |= bit;                                               \
      if (v1 > v2)  b2 |= bit;                                               \
      if (v2 > v3)  b3 |= bit;                                               \
      float nv3 = CUR[i].w + fmaxf(v3, v2);                                  \
      sh = dpp_shr1_negfill_f32(nv3);                                        \
      float nv2 = CUR[i].z + fmaxf(v2, v1);                                  \
      float nv1 = CUR[i].y + fmaxf(v1, v0);                                  \
      float nv0 = CUR[i].x + fmaxf(v0, vs0);                                 \
      v0 = nv0; v1 = nv1; v2 = nv2; v3 = nv3;                                \
      if ((t & 31) == 31) {                                                  \
        int w = t >> 5;                                                      \
        uint4 pk; pk.x = b0; pk.y = b1; pk.z = b2; pk.w = b3;                \
        *(uint4*)&bits[w * 256 + 4 * lane] = pk;                             \
        b0 = b1 = b2 = b3 = 0;                                               \
      }                                                                      \
    }                                                                        \
  }

  for (int c = 0; c < NC_; c += 3) {
    DP_BODY(BA, BC, c);
    if (c + 1 < NC_) DP_BODY(BB, BA, c + 1);
    if (c + 2 < NC_) DP_BODY(BC, BB, c + 2);
  }
#undef DP_BODY

#pragma unroll
  for (int j = 0; j < 4; ++j) dur[4 * lane + j] = 0;
  __syncthreads();

  const int xlen = xlp[b], ylen = ylp[b];
  if (lane == 0) {
    int idx = xlen - 1;
    int t = ylen - 1;
    while (t >= 0) {
      if (idx == 0) { dur[0] += (uint32_t)(t + 1); break; }
      int w = t >> 5, rr = t & 31;
      uint32_t word = bits[w * 256 + idx];
      word &= (rr == 31) ? 0xffffffffu : ((1u << (rr + 1)) - 1u);
      while (word == 0 && w > 0) { --w; word = bits[w * 256 + idx]; }
      if (word == 0) { dur[idx] += (uint32_t)(t + 1); break; }
      int bitpos = 31 - __builtin_clz(word);
      int tp = (w << 5) | bitpos;        // step where diag fires -> decrement
      dur[idx] += (uint32_t)(t - tp + 1);
      --idx;
      t = tp - 1;
    }
  }
  __syncthreads();

  // wave-wide inclusive scan of durations -> cum, dr, and t->x scatter map
  uint32_t d0 = dur[4 * lane], d1 = dur[4 * lane + 1];
  uint32_t d2 = dur[4 * lane + 2], d3 = dur[4 * lane + 3];
  uint32_t own = d0 + d1 + d2 + d3;
  uint32_t s = own;
#pragma unroll
  for (int off = 1; off < 64; off <<= 1) {
    uint32_t n = __shfl_up(s, off);
    if (lane >= off) s += n;
  }
  uint32_t base = s - own;
  uint32_t c0 = base + d0, c1 = c0 + d1, c2 = c1 + d2, c3 = c2 + d3;
  int x = 4 * lane;
  cum_ws[b * TX_ + x]     = (int)c0;
  cum_ws[b * TX_ + x + 1] = (int)c1;
  cum_ws[b * TX_ + x + 2] = (int)c2;
  cum_ws[b * TX_ + x + 3] = (int)c3;
  dr_out[b * TX_ + x]     = (float)d0;
  dr_out[b * TX_ + x + 1] = (float)d1;
  dr_out[b * TX_ + x + 2] = (float)d2;
  dr_out[b * TX_ + x + 3] = (float)d3;
  int* xt = xt_ws + b * TY_;
  for (uint32_t t = c0 - d0; t < c0; ++t) xt[t] = x;
  for (uint32_t t = c1 - d1; t < c1; ++t) xt[t] = x + 1;
  for (uint32_t t = c2 - d2; t < c2; ++t) xt[t] = x + 2;
  for (uint32_t t = c3 - d3; t < c3; ++t) xt[t] = x + 3;
}

// ---------------------------------------------------------------------------
// Kernel C (fused epilogue): blocks [0,TX) write attn rows from cum;
// blocks [TX,TX+H) gather o_en_ex[b,h,t] = t<ylen ? en[b,h,xt[b,t]] : 0.
// ---------------------------------------------------------------------------
__global__ __launch_bounds__(256) void k_epi(
    const int* __restrict__ cum_ws, const int* __restrict__ xt_ws,
    const float* __restrict__ en, const int* __restrict__ ylp,
    float* __restrict__ attn, float* __restrict__ oen)
{
  const int b = blockIdx.y, bx = blockIdx.x, tid = threadIdx.x;
  __shared__ float row[TX_];
  if (bx < TX_) {
    const int x = bx;
    int hi = cum_ws[b * TX_ + x];
    int lo = (x > 0) ? cum_ws[b * TX_ + x - 1] : 0;
    int t0 = tid * 4;
    float4 v;
    v.x = (t0     >= lo && t0     < hi) ? 1.f : 0.f;
    v.y = (t0 + 1 >= lo && t0 + 1 < hi) ? 1.f : 0.f;
    v.z = (t0 + 2 >= lo && t0 + 2 < hi) ? 1.f : 0.f;
    v.w = (t0 + 3 >= lo && t0 + 3 < hi) ? 1.f : 0.f;
    *(float4*)&attn[((size_t)(b * TX_ + x)) * TY_ + t0] = v;
  } else {
    const int h = bx - TX_;
    row[tid] = en[((size_t)(b * H_ + h)) * TX_ + tid];
    __syncthreads();
    const int ylen = ylp[b];
    int t0 = tid * 4;
    int4 xi = *(const int4*)&xt_ws[b * TY_ + t0];
    float4 v;
    v.x = (t0     < ylen) ? row[xi.x & (TX_ - 1)] : 0.f;
    v.y = (t0 + 1 < ylen) ? row[xi.y & (TX_ - 1)] : 0.f;
    v.z = (t0 + 2 < ylen) ? row[xi.z & (TX_ - 1)] : 0.f;
    v.w = (t0 + 3 < ylen) ? row[xi.w & (TX_ - 1)] : 0.f;
    *(float4*)&oen[((size_t)(b * H_ + h)) * TY_ + t0] = v;
  }
}

extern "C" void kernel_launch(void* const* d_in, const int* in_sizes, int n_in,
                              void* d_out, int out_size, void* d_ws, size_t ws_size,
                              hipStream_t stream)
{
  const float* en = (const float*)d_in[0];
  const float* mu = (const float*)d_in[1];
  const float* ls = (const float*)d_in[2];
  const float* y  = (const float*)d_in[3];
  const int*   xl = (const int*)d_in[4];
  const int*   yl = (const int*)d_in[5];

  float* out  = (float*)d_out;
  float* oen  = out;             // [B,H,TY]
  float* logp = out + OFF_LOGP;  // [B,TX,TY]
  float* attn = out + OFF_ATTN;  // [B,TX,TY] (doubles as lpT scratch first)
  float* dr   = out + OFF_DR;    // [B,TX]

  int* cum = (int*)d_ws;               // B*TX ints
  int* xt  = cum + B_ * TX_;           // B*TY ints

  k_logp<<<dim3(TX_ / 4, B_),   256, 0, stream>>>(mu, ls, y, xl, yl, logp, attn);
  k_dp  <<<B_,                   64, 0, stream>>>(attn, xl, yl, dr, cum, xt);
  k_epi <<<dim3(TX_ + H_, B_),  256, 0, stream>>>(cum, xt, en, yl, attn, oen);
}